// Round 2
// baseline (1081.258 us; speedup 1.0000x reference)
//
#include <hip/hip_runtime.h>
#include <cmath>

// Problem constants: x [B=8, C=256, H=80, W=80] fp32
#define BB 8
#define CC 256
#define HH 80
#define WW 80
#define HWSZ 6400              // 80*80
#define PLANE_FLOATS (CC * HWSZ)      // per-batch floats = 1,638,400
#define TENSOR_FLOATS (BB * PLANE_FLOATS) // 13,107,200

__device__ __forceinline__ float gelu_exact(float v) {
    return 0.5f * v * (1.0f + erff(v * 0.70710678118654752440f));
}

// ---------------------------------------------------------------------------
// Kernel 1: BatchNorm (inference) + spectral gating as 40-tap circular conv
// along W.  out = a_c * h + b_c * (g (*) h)_rows,  h = BN(x).
// One block per (b,c) plane; plane staged in LDS.
// ---------------------------------------------------------------------------
struct GTab { float g[40]; };   // odd taps g[2*jj+1]

__global__ __launch_bounds__(256)
void bn_gate_kernel(const float* __restrict__ x,
                    const float* __restrict__ gamma, const float* __restrict__ beta,
                    const float* __restrict__ mean,  const float* __restrict__ var,
                    const float* __restrict__ ar,    const float* __restrict__ ai,
                    float* __restrict__ out, GTab gt)
{
    __shared__ float sv[HWSZ];
    const int blk = blockIdx.x;          // b*256 + c
    const int c = blk & (CC - 1);
    const float sc = gamma[c] * rsqrtf(var[c] + 1e-5f);
    const float sh = beta[c] - mean[c] * sc;
    const float a = ar[c], bgate = ai[c];
    const size_t base = (size_t)blk * HWSZ;

    // stage BN(x) into LDS, vectorized
    const float4* x4 = (const float4*)(x + base);
    float4* s4 = (float4*)sv;
    for (int i = threadIdx.x; i < HWSZ / 4; i += 256) {
        float4 v = x4[i];
        v.x = fmaf(sc, v.x, sh); v.y = fmaf(sc, v.y, sh);
        v.z = fmaf(sc, v.z, sh); v.w = fmaf(sc, v.w, sh);
        s4[i] = v;
    }
    __syncthreads();

    for (int i = threadIdx.x; i < HWSZ; i += 256) {
        const int y = i / WW;
        const int xx = i - y * WW;
        const float* row = sv + y * WW;
        float acc = 0.0f;
#pragma unroll
        for (int jj = 0; jj < 40; ++jj) {
            const int j = 2 * jj + 1;
            int idx = xx - j;
            idx += (idx >> 31) & WW;     // wrap negative
            acc = fmaf(gt.g[jj], row[idx], acc);
        }
        out[base + i] = fmaf(a, row[xx], bgate * acc);
    }
}

// ---------------------------------------------------------------------------
// Kernel 2: fp32 GEMM for conv1x1.  Per batch b: Y[o,n] = sum_c W[o,c] X[c,n].
// X,Y: [B,256,6400].  W row-major [256, wld] (pointer may be pre-offset).
// 128x128 tile, BK=16, 256 threads, 8x8 micro-tile, global->reg prefetch.
// EPI: 0 = +bias, 1 = +bias+gelu, 2 = +bias+residual, 3 = accumulate (no bias)
// ---------------------------------------------------------------------------
template <int EPI>
__global__ __launch_bounds__(256)
void gemm256_kernel(const float* __restrict__ X, const float* __restrict__ W,
                    const int wld, const float* __restrict__ bias,
                    const float* __restrict__ res, float* __restrict__ Y)
{
    __shared__ float sW[16][128];
    __shared__ float sX[16][128];

    const int bz = blockIdx.z;
    const int oBase = blockIdx.y * 128;
    const int nBase = blockIdx.x * 128;
    const int t = threadIdx.x;
    const int tx = t & 15, ty = t >> 4;

    const float* Xb = X + (size_t)bz * PLANE_FLOATS;
    float* Yb = Y + (size_t)bz * PLANE_FLOATS;

    float acc[8][8];
#pragma unroll
    for (int i = 0; i < 8; ++i)
#pragma unroll
        for (int j = 0; j < 8; ++j) acc[i][j] = 0.0f;

    // load-thread mappings
    const int wo = t >> 1;           // 0..127 (o within tile)
    const int wk = (t & 1) * 8;      // 0 or 8 (k group)
    const int xk = t >> 5;           // 0..7   (k row)
    const int xn = (t & 31) * 4;     // 0..124 (n within tile)

    const float* wrow = W + (size_t)(oBase + wo) * wld;
    const float* xcol = Xb + nBase + xn;

    // prefetch kb = 0
    float4 w0 = *(const float4*)&wrow[wk];
    float4 w1 = *(const float4*)&wrow[wk + 4];
    float4 x0 = *(const float4*)&xcol[(size_t)xk * HWSZ];
    float4 x1 = *(const float4*)&xcol[(size_t)(xk + 8) * HWSZ];

    for (int kb = 0; kb < 256; kb += 16) {
        __syncthreads();   // previous iteration's LDS reads done
        sW[wk + 0][wo] = w0.x; sW[wk + 1][wo] = w0.y;
        sW[wk + 2][wo] = w0.z; sW[wk + 3][wo] = w0.w;
        sW[wk + 4][wo] = w1.x; sW[wk + 5][wo] = w1.y;
        sW[wk + 6][wo] = w1.z; sW[wk + 7][wo] = w1.w;
        *(float4*)&sX[xk][xn]     = x0;
        *(float4*)&sX[xk + 8][xn] = x1;
        __syncthreads();

        // prefetch next K-tile while computing this one
        if (kb + 16 < 256) {
            w0 = *(const float4*)&wrow[kb + 16 + wk];
            w1 = *(const float4*)&wrow[kb + 16 + wk + 4];
            x0 = *(const float4*)&xcol[(size_t)(kb + 16 + xk) * HWSZ];
            x1 = *(const float4*)&xcol[(size_t)(kb + 16 + xk + 8) * HWSZ];
        }

#pragma unroll
        for (int k = 0; k < 16; ++k) {
            const float4 a0 = *(const float4*)&sW[k][ty * 4];
            const float4 a1 = *(const float4*)&sW[k][ty * 4 + 64];
            const float4 b0 = *(const float4*)&sX[k][tx * 4];
            const float4 b1 = *(const float4*)&sX[k][tx * 4 + 64];
            const float av[8] = {a0.x, a0.y, a0.z, a0.w, a1.x, a1.y, a1.z, a1.w};
            const float bv[8] = {b0.x, b0.y, b0.z, b0.w, b1.x, b1.y, b1.z, b1.w};
#pragma unroll
            for (int i = 0; i < 8; ++i)
#pragma unroll
                for (int j = 0; j < 8; ++j)
                    acc[i][j] = fmaf(av[i], bv[j], acc[i][j]);
        }
    }

    // epilogue
#pragma unroll
    for (int i = 0; i < 8; ++i) {
        const int o = oBase + ty * 4 + (i & 3) + ((i >> 2) << 6);
        float* yrow = Yb + (size_t)o * HWSZ + nBase;
        const float bo = (EPI == 3) ? 0.0f : bias[o];
        const float* rrow = (EPI == 2)
            ? (res + ((size_t)bz * CC + o) * HWSZ + nBase) : nullptr;
#pragma unroll
        for (int jh = 0; jh < 2; ++jh) {
            const int n0 = tx * 4 + (jh << 6);
            float v[4];
#pragma unroll
            for (int e = 0; e < 4; ++e) v[e] = acc[i][jh * 4 + e] + bo;
            if (EPI == 1) {
#pragma unroll
                for (int e = 0; e < 4; ++e) v[e] = gelu_exact(v[e]);
            }
            if (EPI == 2) {
                const float4 r = *(const float4*)&rrow[n0];
                v[0] += r.x; v[1] += r.y; v[2] += r.z; v[3] += r.w;
            }
            if (EPI == 3) {
                const float4 p = *(const float4*)&yrow[n0];
                v[0] += p.x; v[1] += p.y; v[2] += p.z; v[3] += p.w;
            }
            float4 outv; outv.x = v[0]; outv.y = v[1]; outv.z = v[2]; outv.w = v[3];
            *(float4*)&yrow[n0] = outv;
        }
    }
}

// ---------------------------------------------------------------------------
// Kernel 3: depthwise 3x3 (SAME, zero pad) + bias + exact GELU
// ---------------------------------------------------------------------------
__global__ __launch_bounds__(256)
void dwconv_gelu_kernel(const float* __restrict__ in, const float* __restrict__ w,
                        const float* __restrict__ bias, float* __restrict__ out)
{
    const int idx = blockIdx.x * 256 + threadIdx.x;  // < 13107200
    const int plane = idx / HWSZ;                    // b*256 + c
    const int pix = idx - plane * HWSZ;
    const int c = plane & (CC - 1);
    const int y = pix / WW;
    const int xx = pix - y * WW;
    const float* p = in + (size_t)plane * HWSZ;
    const float* wc = w + c * 9;

    float s = bias[c];
#pragma unroll
    for (int ky = 0; ky < 3; ++ky) {
        const int yy = y + ky - 1;
        if (yy < 0 || yy >= HH) continue;
        const float* prow = p + yy * WW;
#pragma unroll
        for (int kx = 0; kx < 3; ++kx) {
            const int xx2 = xx + kx - 1;
            if (xx2 < 0 || xx2 >= WW) continue;
            s = fmaf(wc[ky * 3 + kx], prow[xx2], s);
        }
    }
    out[idx] = gelu_exact(s);
}

// ---------------------------------------------------------------------------
extern "C" void kernel_launch(void* const* d_in, const int* in_sizes, int n_in,
                              void* d_out, int out_size, void* d_ws, size_t ws_size,
                              hipStream_t stream)
{
    const float* x        = (const float*)d_in[0];
    const float* bn_gamma = (const float*)d_in[1];
    const float* bn_beta  = (const float*)d_in[2];
    const float* bn_mean  = (const float*)d_in[3];
    const float* bn_var   = (const float*)d_in[4];
    const float* alpha_r  = (const float*)d_in[5];
    const float* alpha_i  = (const float*)d_in[6];
    const float* pi_w     = (const float*)d_in[7];
    const float* pi_b     = (const float*)d_in[8];
    const float* dw_w     = (const float*)d_in[9];
    const float* dw_b     = (const float*)d_in[10];
    const float* fpw_w    = (const float*)d_in[11];
    const float* fpw_b    = (const float*)d_in[12];
    const float* ffn1_w   = (const float*)d_in[13];
    const float* ffn1_b   = (const float*)d_in[14];
    const float* ffn2_w   = (const float*)d_in[15];
    const float* ffn2_b   = (const float*)d_in[16];
    const float* po_w     = (const float*)d_in[17];
    const float* po_b     = (const float*)d_in[18];
    const float* post_w   = (const float*)d_in[19];
    const float* post_b   = (const float*)d_in[20];

    // workspace layout: 3 activation buffers in ws; d_out doubles as 4th
    float* bufA = (float*)d_ws;                       // h (gated)  — residual for po
    float* bufB = bufA + TENSOR_FLOATS;               // t / y2 / h2
    float* bufC = bufB + TENSOR_FLOATS;               // y1 / y3a / y3b
    float* bufD = (float*)d_out;                      // y4 accumulator (scratch), final out

    // Hilbert-like gating kernel taps (host, double precision)
    GTab gt;
    for (int jj = 0; jj < 40; ++jj) {
        const int j = 2 * jj + 1;
        double s = 0.0;
        for (int k = 1; k <= 39; ++k)
            s += sin(2.0 * 3.14159265358979323846 * (double)k * (double)j / 80.0);
        gt.g[jj] = (float)(-s / 40.0);
    }

    const dim3 gGrid(HWSZ / 128, CC / 128, BB);   // 50 x 2 x 8
    const dim3 gBlk(256);

    // 1. BN + spectral gating -> bufA  (this is res2)
    bn_gate_kernel<<<BB * CC, 256, 0, stream>>>(x, bn_gamma, bn_beta, bn_mean,
                                                bn_var, alpha_r, alpha_i, bufA, gt);
    // 2. proj_in 1x1 -> bufB
    gemm256_kernel<0><<<gGrid, gBlk, 0, stream>>>(bufA, pi_w, 256, pi_b, nullptr, bufB);
    // 3. dw3x3 + bias + GELU -> bufC
    dwconv_gelu_kernel<<<TENSOR_FLOATS / 256, 256, 0, stream>>>(bufB, dw_w, dw_b, bufC);
    // 4. fpw 1x1 -> bufB (y2)
    gemm256_kernel<0><<<gGrid, gBlk, 0, stream>>>(bufC, fpw_w, 256, fpw_b, nullptr, bufB);
    // 5a. ffn1 rows [0,256) + GELU -> bufC
    gemm256_kernel<1><<<gGrid, gBlk, 0, stream>>>(bufB, ffn1_w, 256, ffn1_b, nullptr, bufC);
    // 6a. ffn2 cols [0,256) + bias -> bufD
    gemm256_kernel<0><<<gGrid, gBlk, 0, stream>>>(bufC, ffn2_w, 512, ffn2_b, nullptr, bufD);
    // 5b. ffn1 rows [256,512) + GELU -> bufC
    gemm256_kernel<1><<<gGrid, gBlk, 0, stream>>>(bufB, ffn1_w + 256 * 256, 256,
                                                  ffn1_b + 256, nullptr, bufC);
    // 6b. ffn2 cols [256,512) accumulate -> bufD (y4)
    gemm256_kernel<3><<<gGrid, gBlk, 0, stream>>>(bufC, ffn2_w + 256, 512,
                                                  nullptr, nullptr, bufD);
    // 7. proj_out 1x1 + res2(bufA) -> bufB (h2)
    gemm256_kernel<2><<<gGrid, gBlk, 0, stream>>>(bufD, po_w, 256, po_b, bufA, bufB);
    // 8. post 1x1 + res(x) -> d_out
    gemm256_kernel<2><<<gGrid, gBlk, 0, stream>>>(bufB, post_w, 256, post_b, x,
                                                  (float*)d_out);
}

// Round 3
// 591.449 us; speedup vs baseline: 1.8282x; 1.8282x over previous
//
#include <hip/hip_runtime.h>
#include <cmath>

// Problem constants: x [B=8, C=256, H=80, W=80] fp32
#define BB 8
#define CC 256
#define HH 80
#define WW 80
#define HWSZ 6400              // 80*80
#define PLANE_FLOATS (CC * HWSZ)      // per-batch floats = 1,638,400
#define TENSOR_FLOATS (BB * PLANE_FLOATS) // 13,107,200

using short8v = __attribute__((ext_vector_type(8))) short;
using f32x4  = __attribute__((ext_vector_type(4))) float;

__device__ __forceinline__ float gelu_exact(float v) {
    return 0.5f * v * (1.0f + erff(v * 0.70710678118654752440f));
}

// fp32 -> bf16 (RNE), manual to avoid header-type friction
__device__ __forceinline__ unsigned short f2bf(float f) {
    unsigned int u = __float_as_uint(f);
    unsigned int r = (u + 0x7FFFu + ((u >> 16) & 1u)) >> 16;
    return (unsigned short)r;
}
__device__ __forceinline__ float bf2f(unsigned short h) {
    return __uint_as_float(((unsigned int)h) << 16);
}

// ---------------------------------------------------------------------------
// Kernel 0: preconvert weights fp32 -> bf16 hi/lo in A-fragment order.
// Layout (ushort elems): idx = ((ks*16 + fi)*64 + l)*8 + j, where the element
// is W[o][c] with o = fi*16 + (l&15), c = ks*32 + ((l>>4))*8 + j.
// ---------------------------------------------------------------------------
struct PreAll {
    const float* src[7];
    int stride[7];   // src row stride (floats)
    int runs[7];     // ksteps*1024
    int dstOff[7];   // ushort offset into pack arrays
};

__global__ __launch_bounds__(256)
void preconvert_kernel(PreAll d, unsigned short* __restrict__ packH,
                       unsigned short* __restrict__ packL)
{
    const int m = blockIdx.y;
    const int r = blockIdx.x * 256 + threadIdx.x;
    if (r >= d.runs[m]) return;
    const int ks = r >> 10;
    const int rem = r & 1023;
    const int fi = rem >> 6;
    const int l = rem & 63;
    const int o = fi * 16 + (l & 15);
    const int c0 = ks * 32 + ((l >> 4)) * 8;
    const float* src = d.src[m] + (size_t)o * d.stride[m] + c0;
    short8v hv, lv;
#pragma unroll
    for (int j = 0; j < 8; ++j) {
        const float v = src[j];
        const unsigned short h = f2bf(v);
        const unsigned short lo = f2bf(v - bf2f(h));
        hv[j] = (short)h; lv[j] = (short)lo;
    }
    *(short8v*)(packH + d.dstOff[m] + (size_t)r * 8) = hv;
    *(short8v*)(packL + d.dstOff[m] + (size_t)r * 8) = lv;
}

// ---------------------------------------------------------------------------
// Kernel 1: BatchNorm (inference) + spectral gating as 40-tap circular conv
// along W.  out = a_c * h + b_c * (g (*) h)_rows,  h = BN(x).  (unchanged)
// ---------------------------------------------------------------------------
struct GTab { float g[40]; };   // odd taps g[2*jj+1]

__global__ __launch_bounds__(256)
void bn_gate_kernel(const float* __restrict__ x,
                    const float* __restrict__ gamma, const float* __restrict__ beta,
                    const float* __restrict__ mean,  const float* __restrict__ var,
                    const float* __restrict__ ar,    const float* __restrict__ ai,
                    float* __restrict__ out, GTab gt)
{
    __shared__ float sv[HWSZ];
    const int blk = blockIdx.x;          // b*256 + c
    const int c = blk & (CC - 1);
    const float sc = gamma[c] * rsqrtf(var[c] + 1e-5f);
    const float sh = beta[c] - mean[c] * sc;
    const float a = ar[c], bgate = ai[c];
    const size_t base = (size_t)blk * HWSZ;

    const float4* x4 = (const float4*)(x + base);
    float4* s4 = (float4*)sv;
    for (int i = threadIdx.x; i < HWSZ / 4; i += 256) {
        float4 v = x4[i];
        v.x = fmaf(sc, v.x, sh); v.y = fmaf(sc, v.y, sh);
        v.z = fmaf(sc, v.z, sh); v.w = fmaf(sc, v.w, sh);
        s4[i] = v;
    }
    __syncthreads();

    for (int i = threadIdx.x; i < HWSZ; i += 256) {
        const int y = i / WW;
        const int xx = i - y * WW;
        const float* row = sv + y * WW;
        float acc = 0.0f;
#pragma unroll
        for (int jj = 0; jj < 40; ++jj) {
            const int j = 2 * jj + 1;
            int idx = xx - j;
            idx += (idx >> 31) & WW;     // wrap negative
            acc = fmaf(gt.g[jj], row[idx], acc);
        }
        out[base + i] = fmaf(a, row[xx], bgate * acc);
    }
}

// ---------------------------------------------------------------------------
// Kernel 2: MFMA bf16-split-3 GEMM for conv1x1.
// Per batch: Y[o,n] = sum_c W[o,c] X[c,n], M=256 (full), N-tile=64, K=256.
// 256 threads = 4 waves; wave w computes o in [w*64, w*64+64).
// A (weights) pre-packed hi/lo, fragment-ordered -> direct global->VGPR loads.
// B (X) converted in-kernel, staged via LDS in fragment order.
// EPI: 0 = +bias, 1 = +bias+gelu, 2 = +bias+residual, 3 = accumulate (no bias)
// ---------------------------------------------------------------------------
template <int EPI>
__global__ __launch_bounds__(256)
void gemm_mfma(const float* __restrict__ X,
               const unsigned short* __restrict__ Wh,
               const unsigned short* __restrict__ Wl,
               const float* __restrict__ bias,
               const float* __restrict__ res, float* __restrict__ Y)
{
    __shared__ short8v sBh[256];   // [nt(4)][lane(64)]
    __shared__ short8v sBl[256];

    const int bz = blockIdx.z;
    const int nBase = blockIdx.x * 64;
    const int t = threadIdx.x;
    const int l = t & 63;
    const int w = t >> 6;

    const float* Xb = X + (size_t)bz * PLANE_FLOATS + nBase;
    float* Yb = Y + (size_t)bz * PLANE_FLOATS;

    // staging role: thread owns (n = t&63, c-run = (t>>6)*8 .. +7) per K32 step
    const int sn = t & 63;
    const int scg = t >> 6;
    const float* xcol = Xb + sn;
    const int slot = ((sn >> 4) * 64) + scg * 16 + (sn & 15);  // nt*64 + lane

    f32x4 acc[4][4];
#pragma unroll
    for (int m = 0; m < 4; ++m)
#pragma unroll
        for (int n2 = 0; n2 < 4; ++n2) acc[m][n2] = (f32x4){0.f, 0.f, 0.f, 0.f};

    // prefetch ks = 0
    float xv[8], xv2[8];
#pragma unroll
    for (int j = 0; j < 8; ++j)
        xv[j] = xcol[(size_t)(scg * 8 + j) * HWSZ];

    for (int ks = 0; ks < 8; ++ks) {
        // convert current tile
        short8v hv, lv;
#pragma unroll
        for (int j = 0; j < 8; ++j) {
            const unsigned short h = f2bf(xv[j]);
            const unsigned short lo = f2bf(xv[j] - bf2f(h));
            hv[j] = (short)h; lv[j] = (short)lo;
        }
        __syncthreads();               // prior iteration's LDS reads complete
        sBh[slot] = hv;
        sBl[slot] = lv;
        // issue next tile's global loads (latency hides under MFMA phase)
        if (ks < 7) {
#pragma unroll
            for (int j = 0; j < 8; ++j)
                xv2[j] = xcol[(size_t)((ks + 1) * 32 + scg * 8 + j) * HWSZ];
        }
        __syncthreads();

        // A fragments: direct global loads (L2-hot packed weights)
        const size_t fbase = ((size_t)(ks * 16 + w * 4) * 64 + l) * 8;
        short8v ah[4], al[4];
#pragma unroll
        for (int m = 0; m < 4; ++m) {
            ah[m] = *(const short8v*)(Wh + fbase + (size_t)m * 64 * 8);
            al[m] = *(const short8v*)(Wl + fbase + (size_t)m * 64 * 8);
        }
        // B fragments from LDS (lane-linear, conflict-free)
        short8v bh[4], bl[4];
#pragma unroll
        for (int n2 = 0; n2 < 4; ++n2) {
            bh[n2] = sBh[n2 * 64 + l];
            bl[n2] = sBl[n2 * 64 + l];
        }
        // split-3 MFMA
#pragma unroll
        for (int m = 0; m < 4; ++m)
#pragma unroll
            for (int n2 = 0; n2 < 4; ++n2) {
                acc[m][n2] = __builtin_amdgcn_mfma_f32_16x16x32_bf16(
                    ah[m], bh[n2], acc[m][n2], 0, 0, 0);
                acc[m][n2] = __builtin_amdgcn_mfma_f32_16x16x32_bf16(
                    ah[m], bl[n2], acc[m][n2], 0, 0, 0);
                acc[m][n2] = __builtin_amdgcn_mfma_f32_16x16x32_bf16(
                    al[m], bh[n2], acc[m][n2], 0, 0, 0);
            }
#pragma unroll
        for (int j = 0; j < 8; ++j) xv[j] = xv2[j];
    }

    // epilogue: C/D layout col = l&15, row = (l>>4)*4 + r  (m89-verified)
    const int col = l & 15, g = l >> 4;
#pragma unroll
    for (int m = 0; m < 4; ++m) {
        const int o0 = w * 64 + m * 16 + g * 4;
#pragma unroll
        for (int r = 0; r < 4; ++r) {
            const int o = o0 + r;
            const float bo = (EPI == 3) ? 0.0f : bias[o];
            float* yrow = Yb + (size_t)o * HWSZ + nBase;
            const float* rrow = (EPI == 2)
                ? (res + ((size_t)bz * CC + o) * HWSZ + nBase) : nullptr;
#pragma unroll
            for (int n2 = 0; n2 < 4; ++n2) {
                const int n = n2 * 16 + col;
                float v = acc[m][n2][r] + bo;
                if (EPI == 1) v = gelu_exact(v);
                if (EPI == 2) v += rrow[n];
                if (EPI == 3) v += yrow[n];
                yrow[n] = v;
            }
        }
    }
}

// ---------------------------------------------------------------------------
// Kernel 3: depthwise 3x3 (SAME, zero pad) + bias + exact GELU  (unchanged)
// ---------------------------------------------------------------------------
__global__ __launch_bounds__(256)
void dwconv_gelu_kernel(const float* __restrict__ in, const float* __restrict__ w,
                        const float* __restrict__ bias, float* __restrict__ out)
{
    const int idx = blockIdx.x * 256 + threadIdx.x;  // < 13107200
    const int plane = idx / HWSZ;                    // b*256 + c
    const int pix = idx - plane * HWSZ;
    const int c = plane & (CC - 1);
    const int y = pix / WW;
    const int xx = pix - y * WW;
    const float* p = in + (size_t)plane * HWSZ;
    const float* wc = w + c * 9;

    float s = bias[c];
#pragma unroll
    for (int ky = 0; ky < 3; ++ky) {
        const int yy = y + ky - 1;
        if (yy < 0 || yy >= HH) continue;
        const float* prow = p + yy * WW;
#pragma unroll
        for (int kx = 0; kx < 3; ++kx) {
            const int xx2 = xx + kx - 1;
            if (xx2 < 0 || xx2 >= WW) continue;
            s = fmaf(wc[ky * 3 + kx], prow[xx2], s);
        }
    }
    out[idx] = gelu_exact(s);
}

// ---------------------------------------------------------------------------
extern "C" void kernel_launch(void* const* d_in, const int* in_sizes, int n_in,
                              void* d_out, int out_size, void* d_ws, size_t ws_size,
                              hipStream_t stream)
{
    const float* x        = (const float*)d_in[0];
    const float* bn_gamma = (const float*)d_in[1];
    const float* bn_beta  = (const float*)d_in[2];
    const float* bn_mean  = (const float*)d_in[3];
    const float* bn_var   = (const float*)d_in[4];
    const float* alpha_r  = (const float*)d_in[5];
    const float* alpha_i  = (const float*)d_in[6];
    const float* pi_w     = (const float*)d_in[7];
    const float* pi_b     = (const float*)d_in[8];
    const float* dw_w     = (const float*)d_in[9];
    const float* dw_b     = (const float*)d_in[10];
    const float* fpw_w    = (const float*)d_in[11];
    const float* fpw_b    = (const float*)d_in[12];
    const float* ffn1_w   = (const float*)d_in[13];
    const float* ffn1_b   = (const float*)d_in[14];
    const float* ffn2_w   = (const float*)d_in[15];
    const float* ffn2_b   = (const float*)d_in[16];
    const float* po_w     = (const float*)d_in[17];
    const float* po_b     = (const float*)d_in[18];
    const float* post_w   = (const float*)d_in[19];
    const float* post_b   = (const float*)d_in[20];

    float* bufA = (float*)d_ws;                       // gated h (res2)
    float* bufB = bufA + TENSOR_FLOATS;
    float* bufC = bufB + TENSOR_FLOATS;
    float* bufD = (float*)d_out;                      // y4 accumulator / final out
    unsigned short* packH = (unsigned short*)(bufC + TENSOR_FLOATS);
    unsigned short* packL = packH + 524288;

    // gating taps
    GTab gt;
    for (int jj = 0; jj < 40; ++jj) {
        const int j = 2 * jj + 1;
        double s = 0.0;
        for (int k = 1; k <= 39; ++k)
            s += sin(2.0 * 3.14159265358979323846 * (double)k * (double)j / 80.0);
        gt.g[jj] = (float)(-s / 40.0);
    }

    // weight preconvert descriptors: pi, fpw, ffn1a, ffn1b, ffn2, po, post
    PreAll pd;
    pd.src[0] = pi_w;              pd.stride[0] = 256; pd.runs[0] = 8192;  pd.dstOff[0] = 0;
    pd.src[1] = fpw_w;             pd.stride[1] = 256; pd.runs[1] = 8192;  pd.dstOff[1] = 65536;
    pd.src[2] = ffn1_w;            pd.stride[2] = 256; pd.runs[2] = 8192;  pd.dstOff[2] = 131072;
    pd.src[3] = ffn1_w + 256*256;  pd.stride[3] = 256; pd.runs[3] = 8192;  pd.dstOff[3] = 196608;
    pd.src[4] = ffn2_w;            pd.stride[4] = 512; pd.runs[4] = 16384; pd.dstOff[4] = 262144;
    pd.src[5] = po_w;              pd.stride[5] = 256; pd.runs[5] = 8192;  pd.dstOff[5] = 393216;
    pd.src[6] = post_w;            pd.stride[6] = 256; pd.runs[6] = 8192;  pd.dstOff[6] = 458752;

    const dim3 gGrid(HWSZ / 64, 1, BB);   // 100 x 1 x 8
    const dim3 gBlk(256);

    // 0. preconvert weights
    preconvert_kernel<<<dim3(64, 7), 256, 0, stream>>>(pd, packH, packL);
    // 1. BN + spectral gating -> bufA  (res2)
    bn_gate_kernel<<<BB * CC, 256, 0, stream>>>(x, bn_gamma, bn_beta, bn_mean,
                                                bn_var, alpha_r, alpha_i, bufA, gt);
    // 2. proj_in 1x1 -> bufB
    gemm_mfma<0><<<gGrid, gBlk, 0, stream>>>(bufA, packH + 0, packL + 0, pi_b, nullptr, bufB);
    // 3. dw3x3 + bias + GELU -> bufC
    dwconv_gelu_kernel<<<TENSOR_FLOATS / 256, 256, 0, stream>>>(bufB, dw_w, dw_b, bufC);
    // 4. fpw 1x1 -> bufB (y2)
    gemm_mfma<0><<<gGrid, gBlk, 0, stream>>>(bufC, packH + 65536, packL + 65536, fpw_b, nullptr, bufB);
    // 5a. ffn1 rows [0,256) + GELU -> bufC
    gemm_mfma<1><<<gGrid, gBlk, 0, stream>>>(bufB, packH + 131072, packL + 131072, ffn1_b, nullptr, bufC);
    // 6a. ffn2 k-cols [0,256) + bias -> bufD
    gemm_mfma<0><<<gGrid, gBlk, 0, stream>>>(bufC, packH + 262144, packL + 262144, ffn2_b, nullptr, bufD);
    // 5b. ffn1 rows [256,512) + GELU -> bufC
    gemm_mfma<1><<<gGrid, gBlk, 0, stream>>>(bufB, packH + 196608, packL + 196608, ffn1_b + 256, nullptr, bufC);
    // 6b. ffn2 k-cols [256,512) accumulate -> bufD (y4)
    gemm_mfma<3><<<gGrid, gBlk, 0, stream>>>(bufC, packH + 262144 + 65536, packL + 262144 + 65536,
                                             ffn2_b, nullptr, bufD);
    // 7. proj_out 1x1 + res2(bufA) -> bufB (h2)
    gemm_mfma<2><<<gGrid, gBlk, 0, stream>>>(bufD, packH + 393216, packL + 393216, po_b, bufA, bufB);
    // 8. post 1x1 + res(x) -> d_out
    gemm_mfma<2><<<gGrid, gBlk, 0, stream>>>(bufB, packH + 458752, packL + 458752, post_b, x,
                                             (float*)d_out);
}

// Round 4
// 426.292 us; speedup vs baseline: 2.5364x; 1.3874x over previous
//
#include <hip/hip_runtime.h>
#include <cmath>

// Problem constants: x [B=8, C=256, H=80, W=80] fp32
#define BB 8
#define CC 256
#define HH 80
#define WW 80
#define HWSZ 6400              // 80*80
#define PLANE_FLOATS (CC * HWSZ)      // per-batch floats = 1,638,400
#define TENSOR_FLOATS (BB * PLANE_FLOATS) // 13,107,200

using short8v = __attribute__((ext_vector_type(8))) short;
using f32x4  = __attribute__((ext_vector_type(4))) float;

__device__ __forceinline__ float gelu_exact(float v) {
    return 0.5f * v * (1.0f + erff(v * 0.70710678118654752440f));
}

// fp32 -> bf16 (RNE)
__device__ __forceinline__ unsigned short f2bf(float f) {
    unsigned int u = __float_as_uint(f);
    unsigned int r = (u + 0x7FFFu + ((u >> 16) & 1u)) >> 16;
    return (unsigned short)r;
}
__device__ __forceinline__ float bf2f(unsigned short h) {
    return __uint_as_float(((unsigned int)h) << 16);
}

// ---------------------------------------------------------------------------
// Kernel 0: preconvert weights fp32 -> bf16 hi/lo in A-fragment order.
// idx = ((ks*16 + fi)*64 + l)*8 + j; element W[o][c], o = fi*16 + (l&15),
// c = ks*32 + (l>>4)*8 + j.
// ---------------------------------------------------------------------------
struct PreAll {
    const float* src[7];
    int stride[7];
    int runs[7];     // ksteps*1024
    int dstOff[7];
};

__global__ __launch_bounds__(256)
void preconvert_kernel(PreAll d, unsigned short* __restrict__ packH,
                       unsigned short* __restrict__ packL)
{
    const int m = blockIdx.y;
    const int r = blockIdx.x * 256 + threadIdx.x;
    if (r >= d.runs[m]) return;
    const int ks = r >> 10;
    const int rem = r & 1023;
    const int fi = rem >> 6;
    const int l = rem & 63;
    const int o = fi * 16 + (l & 15);
    const int c0 = ks * 32 + ((l >> 4)) * 8;
    const float* src = d.src[m] + (size_t)o * d.stride[m] + c0;
    short8v hv, lv;
#pragma unroll
    for (int j = 0; j < 8; ++j) {
        const float v = src[j];
        const unsigned short h = f2bf(v);
        const unsigned short lo = f2bf(v - bf2f(h));
        hv[j] = (short)h; lv[j] = (short)lo;
    }
    *(short8v*)(packH + d.dstOff[m] + (size_t)r * 8) = hv;
    *(short8v*)(packL + d.dstOff[m] + (size_t)r * 8) = lv;
}

// ---------------------------------------------------------------------------
// Kernel 1: BN + spectral gating. 8 outputs/thread, 22 aligned ds_read_b128
// into statically-indexed register window; taps g[] live in SGPRs (kernarg).
// ---------------------------------------------------------------------------
struct GTab { float g[40]; };   // odd taps g[2*jj+1]

__global__ __launch_bounds__(256)
void bn_gate_kernel(const float* __restrict__ x,
                    const float* __restrict__ gamma, const float* __restrict__ beta,
                    const float* __restrict__ mean,  const float* __restrict__ var,
                    const float* __restrict__ ar,    const float* __restrict__ ai,
                    float* __restrict__ out, GTab gt)
{
    __shared__ float sv[HWSZ];
    const int blk = blockIdx.x;          // b*256 + c
    const int c = blk & (CC - 1);
    const float sc = gamma[c] * rsqrtf(var[c] + 1e-5f);
    const float sh = beta[c] - mean[c] * sc;
    const float a = ar[c], bgate = ai[c];
    const size_t base = (size_t)blk * HWSZ;

    const float4* x4 = (const float4*)(x + base);
    float4* s4 = (float4*)sv;
    for (int i = threadIdx.x; i < HWSZ / 4; i += 256) {
        float4 v = x4[i];
        v.x = fmaf(sc, v.x, sh); v.y = fmaf(sc, v.y, sh);
        v.z = fmaf(sc, v.z, sh); v.w = fmaf(sc, v.w, sh);
        s4[i] = v;
    }
    __syncthreads();

    // 800 groups of 8 consecutive outputs per plane
#pragma unroll 1
    for (int r = 0; r < 4; ++r) {
        const int gi = r * 256 + threadIdx.x;
        if (gi >= 800) break;
        const int y = gi / 10;
        const int x0 = (gi - y * 10) * 8;
        const float* row = sv + y * WW;

        // rbuf[k] = row[(x0 + k) mod 80], k = 0..87 — static indices only
        float rbuf[88];
#pragma unroll
        for (int q = 0; q < 22; ++q) {
            int col = x0 + 4 * q;
            if (col >= 80) col -= 80;
            const float4 v = *(const float4*)&row[col];
            rbuf[4 * q + 0] = v.x; rbuf[4 * q + 1] = v.y;
            rbuf[4 * q + 2] = v.z; rbuf[4 * q + 3] = v.w;
        }
        float outv[8];
#pragma unroll
        for (int e = 0; e < 8; ++e) {
            float acc = 0.0f;
#pragma unroll
            for (int jj = 0; jj < 40; ++jj) {
                const int j = 2 * jj + 1;          // odd taps
                acc = fmaf(gt.g[jj], rbuf[80 + e - j], acc);
            }
            outv[e] = fmaf(a, rbuf[80 + e], bgate * acc);
        }
        float4 o0 = {outv[0], outv[1], outv[2], outv[3]};
        float4 o1 = {outv[4], outv[5], outv[6], outv[7]};
        *(float4*)&out[base + (size_t)y * WW + x0]     = o0;
        *(float4*)&out[base + (size_t)y * WW + x0 + 4] = o1;
    }
}

// ---------------------------------------------------------------------------
// Kernel 2: MFMA bf16-split-3 GEMM. M=256 full, N-tile=64, K = KS*32.
// LDS double-buffer (1 barrier/K-step); next-step A-frags + X loads issued
// before the MFMA phase. KS=16 reads K 0..255 from X, 256..511 from X2.
// EPI: 0 = +bias, 1 = +bias+gelu, 2 = +bias+residual
// ---------------------------------------------------------------------------
template <int EPI, int KS>
__global__ __launch_bounds__(256)
void gemm_mfma(const float* __restrict__ X, const float* __restrict__ X2,
               const unsigned short* __restrict__ Wh,
               const unsigned short* __restrict__ Wl,
               const float* __restrict__ bias,
               const float* __restrict__ res, float* __restrict__ Y)
{
    __shared__ short8v sB[2][2][256];   // [buf][hi/lo][slot], 16 KB

    const int bz = blockIdx.z;
    const int nBase = blockIdx.x * 64;
    const int t = threadIdx.x;
    const int l = t & 63;
    const int w = t >> 6;

    const float* Xb  = X + (size_t)bz * PLANE_FLOATS + nBase;
    const float* X2b = (KS == 16) ? (X2 + (size_t)bz * PLANE_FLOATS + nBase) : nullptr;
    float* Yb = Y + (size_t)bz * PLANE_FLOATS;

    const int sn = t & 63;
    const int scg = t >> 6;
    const int slot = ((sn >> 4) * 64) + scg * 16 + (sn & 15);

    f32x4 acc[4][4];
#pragma unroll
    for (int m = 0; m < 4; ++m)
#pragma unroll
        for (int n2 = 0; n2 < 4; ++n2) acc[m][n2] = (f32x4){0.f, 0.f, 0.f, 0.f};

    // ---- prologue: stage ks=0, load A ks=0
    float xv[8];
#pragma unroll
    for (int j = 0; j < 8; ++j)
        xv[j] = Xb[(size_t)(scg * 8 + j) * HWSZ + sn];

    short8v ah[4], al[4];
    {
        const size_t fb = ((size_t)(w * 4) * 64 + l) * 8;
#pragma unroll
        for (int m = 0; m < 4; ++m) {
            ah[m] = *(const short8v*)(Wh + fb + (size_t)m * 512);
            al[m] = *(const short8v*)(Wl + fb + (size_t)m * 512);
        }
    }
    {
        short8v hv, lv;
#pragma unroll
        for (int j = 0; j < 8; ++j) {
            const unsigned short h = f2bf(xv[j]);
            const unsigned short lo = f2bf(xv[j] - bf2f(h));
            hv[j] = (short)h; lv[j] = (short)lo;
        }
        sB[0][0][slot] = hv; sB[0][1][slot] = lv;
    }
    __syncthreads();

#pragma unroll
    for (int ks = 0; ks < KS; ++ks) {
        const int p = ks & 1;
        // 1. issue next X loads (in flight across MFMA phase)
        float xv2[8];
        if (ks < KS - 1) {
            const int kn = ks + 1;
            const float* src = (KS == 16 && kn >= 8) ? X2b : Xb;
            const int kk = (KS == 16 && kn >= 8) ? kn - 8 : kn;
#pragma unroll
            for (int j = 0; j < 8; ++j)
                xv2[j] = src[(size_t)(kk * 32 + scg * 8 + j) * HWSZ + sn];
        }
        // 2. B frags from LDS (lane-linear)
        short8v bh[4], bl[4];
#pragma unroll
        for (int n2 = 0; n2 < 4; ++n2) {
            bh[n2] = sB[p][0][n2 * 64 + l];
            bl[n2] = sB[p][1][n2 * 64 + l];
        }
        // 3. prefetch next A frags
        short8v ah2[4], al2[4];
        if (ks < KS - 1) {
            const size_t fb = ((size_t)((ks + 1) * 16 + w * 4) * 64 + l) * 8;
#pragma unroll
            for (int m = 0; m < 4; ++m) {
                ah2[m] = *(const short8v*)(Wh + fb + (size_t)m * 512);
                al2[m] = *(const short8v*)(Wl + fb + (size_t)m * 512);
            }
        }
        // 4. split-3 MFMA
#pragma unroll
        for (int m = 0; m < 4; ++m)
#pragma unroll
            for (int n2 = 0; n2 < 4; ++n2) {
                acc[m][n2] = __builtin_amdgcn_mfma_f32_16x16x32_bf16(
                    ah[m], bh[n2], acc[m][n2], 0, 0, 0);
                acc[m][n2] = __builtin_amdgcn_mfma_f32_16x16x32_bf16(
                    ah[m], bl[n2], acc[m][n2], 0, 0, 0);
                acc[m][n2] = __builtin_amdgcn_mfma_f32_16x16x32_bf16(
                    al[m], bh[n2], acc[m][n2], 0, 0, 0);
            }
        // 5. convert+stage next tile, single barrier
        if (ks < KS - 1) {
            short8v hv, lv;
#pragma unroll
            for (int j = 0; j < 8; ++j) {
                const unsigned short h = f2bf(xv2[j]);
                const unsigned short lo = f2bf(xv2[j] - bf2f(h));
                hv[j] = (short)h; lv[j] = (short)lo;
            }
            sB[p ^ 1][0][slot] = hv; sB[p ^ 1][1][slot] = lv;
            __syncthreads();
#pragma unroll
            for (int m = 0; m < 4; ++m) { ah[m] = ah2[m]; al[m] = al2[m]; }
        }
    }

    // epilogue: C/D layout col = l&15, row = (l>>4)*4 + r
    const int col = l & 15, g = l >> 4;
#pragma unroll
    for (int m = 0; m < 4; ++m) {
        const int o0 = w * 64 + m * 16 + g * 4;
#pragma unroll
        for (int r = 0; r < 4; ++r) {
            const int o = o0 + r;
            const float bo = bias[o];
            float* yrow = Yb + (size_t)o * HWSZ + nBase;
            const float* rrow = (EPI == 2)
                ? (res + ((size_t)bz * CC + o) * HWSZ + nBase) : nullptr;
#pragma unroll
            for (int n2 = 0; n2 < 4; ++n2) {
                const int n = n2 * 16 + col;
                float v = acc[m][n2][r] + bo;
                if (EPI == 1) v = gelu_exact(v);
                if (EPI == 2) v += rrow[n];
                yrow[n] = v;
            }
        }
    }
}

// ---------------------------------------------------------------------------
// Kernel 3: depthwise 3x3 + bias + GELU; 4 outputs/thread, float4 loads.
// ---------------------------------------------------------------------------
__global__ __launch_bounds__(256)
void dwconv_gelu_kernel(const float* __restrict__ in, const float* __restrict__ w,
                        const float* __restrict__ bias, float* __restrict__ out)
{
    const int g = blockIdx.x * 256 + threadIdx.x;   // < 3,276,800
    const int plane = g / 1600;                     // b*256 + c
    const int pg = g - plane * 1600;
    const int c = plane & (CC - 1);
    const int y = pg / 20;
    const int x0 = (pg - y * 20) * 4;
    const float* p = in + (size_t)plane * HWSZ;

    float rb[3][12];
#pragma unroll
    for (int ky = 0; ky < 3; ++ky) {
        const int yy = y + ky - 1;
        const bool yok = (yy >= 0) && (yy < HH);
        const float* prow = p + yy * WW;
#pragma unroll
        for (int q = 0; q < 3; ++q) {
            const int cx = x0 + 4 * q - 4;
            float4 v = {0.f, 0.f, 0.f, 0.f};
            if (yok && cx >= 0 && cx < WW) v = *(const float4*)&prow[cx];
            rb[ky][4 * q + 0] = v.x; rb[ky][4 * q + 1] = v.y;
            rb[ky][4 * q + 2] = v.z; rb[ky][4 * q + 3] = v.w;
        }
    }
    const float* wc = w + c * 9;
    float wv[9];
#pragma unroll
    for (int k = 0; k < 9; ++k) wv[k] = wc[k];
    const float bo = bias[c];

    float4 res;
    float* rp = (float*)&res;
#pragma unroll
    for (int e = 0; e < 4; ++e) {
        float s = bo;
#pragma unroll
        for (int ky = 0; ky < 3; ++ky)
#pragma unroll
            for (int kx = 0; kx < 3; ++kx)
                s = fmaf(wv[ky * 3 + kx], rb[ky][e + kx + 3], s);
        rp[e] = gelu_exact(s);
    }
    *(float4*)&out[(size_t)plane * HWSZ + (size_t)y * WW + x0] = res;
}

// ---------------------------------------------------------------------------
extern "C" void kernel_launch(void* const* d_in, const int* in_sizes, int n_in,
                              void* d_out, int out_size, void* d_ws, size_t ws_size,
                              hipStream_t stream)
{
    const float* x        = (const float*)d_in[0];
    const float* bn_gamma = (const float*)d_in[1];
    const float* bn_beta  = (const float*)d_in[2];
    const float* bn_mean  = (const float*)d_in[3];
    const float* bn_var   = (const float*)d_in[4];
    const float* alpha_r  = (const float*)d_in[5];
    const float* alpha_i  = (const float*)d_in[6];
    const float* pi_w     = (const float*)d_in[7];
    const float* pi_b     = (const float*)d_in[8];
    const float* dw_w     = (const float*)d_in[9];
    const float* dw_b     = (const float*)d_in[10];
    const float* fpw_w    = (const float*)d_in[11];
    const float* fpw_b    = (const float*)d_in[12];
    const float* ffn1_w   = (const float*)d_in[13];
    const float* ffn1_b   = (const float*)d_in[14];
    const float* ffn2_w   = (const float*)d_in[15];
    const float* ffn2_b   = (const float*)d_in[16];
    const float* po_w     = (const float*)d_in[17];
    const float* po_b     = (const float*)d_in[18];
    const float* post_w   = (const float*)d_in[19];
    const float* post_b   = (const float*)d_in[20];

    float* bufA = (float*)d_ws;                       // gated h (res2)
    float* bufB = bufA + TENSOR_FLOATS;
    float* bufC = bufB + TENSOR_FLOATS;
    float* bufD = (float*)d_out;                      // scratch / final out
    unsigned short* packH = (unsigned short*)(bufC + TENSOR_FLOATS);
    unsigned short* packL = packH + 524288;

    // gating taps
    GTab gt;
    for (int jj = 0; jj < 40; ++jj) {
        const int j = 2 * jj + 1;
        double s = 0.0;
        for (int k = 1; k <= 39; ++k)
            s += sin(2.0 * 3.14159265358979323846 * (double)k * (double)j / 80.0);
        gt.g[jj] = (float)(-s / 40.0);
    }

    // weight preconvert: pi, fpw, ffn1a, ffn1b, ffn2(K512), po, post
    PreAll pd;
    pd.src[0] = pi_w;              pd.stride[0] = 256; pd.runs[0] = 8192;  pd.dstOff[0] = 0;
    pd.src[1] = fpw_w;             pd.stride[1] = 256; pd.runs[1] = 8192;  pd.dstOff[1] = 65536;
    pd.src[2] = ffn1_w;            pd.stride[2] = 256; pd.runs[2] = 8192;  pd.dstOff[2] = 131072;
    pd.src[3] = ffn1_w + 256*256;  pd.stride[3] = 256; pd.runs[3] = 8192;  pd.dstOff[3] = 196608;
    pd.src[4] = ffn2_w;            pd.stride[4] = 512; pd.runs[4] = 16384; pd.dstOff[4] = 262144;
    pd.src[5] = po_w;              pd.stride[5] = 256; pd.runs[5] = 8192;  pd.dstOff[5] = 393216;
    pd.src[6] = post_w;            pd.stride[6] = 256; pd.runs[6] = 8192;  pd.dstOff[6] = 458752;

    const dim3 gGrid(HWSZ / 64, 1, BB);   // 100 x 1 x 8
    const dim3 gBlk(256);

    // 0. preconvert weights
    preconvert_kernel<<<dim3(64, 7), 256, 0, stream>>>(pd, packH, packL);
    // 1. BN + spectral gating -> bufA (res2)
    bn_gate_kernel<<<BB * CC, 256, 0, stream>>>(x, bn_gamma, bn_beta, bn_mean,
                                                bn_var, alpha_r, alpha_i, bufA, gt);
    // 2. proj_in -> bufB (t)
    gemm_mfma<0, 8><<<gGrid, gBlk, 0, stream>>>(bufA, nullptr, packH, packL,
                                                pi_b, nullptr, bufB);
    // 3. dw3x3 + GELU -> bufC (y1)
    dwconv_gelu_kernel<<<TENSOR_FLOATS / 1024, 256, 0, stream>>>(bufB, dw_w, dw_b, bufC);
    // 4. fpw -> bufB (y2)
    gemm_mfma<0, 8><<<gGrid, gBlk, 0, stream>>>(bufC, nullptr, packH + 65536,
                                                packL + 65536, fpw_b, nullptr, bufB);
    // 5a. ffn1 rows [0,256) + GELU -> bufC (y3a)
    gemm_mfma<1, 8><<<gGrid, gBlk, 0, stream>>>(bufB, nullptr, packH + 131072,
                                                packL + 131072, ffn1_b, nullptr, bufC);
    // 5b. ffn1 rows [256,512) + GELU -> bufD (y3b)
    gemm_mfma<1, 8><<<gGrid, gBlk, 0, stream>>>(bufB, nullptr, packH + 196608,
                                                packL + 196608, ffn1_b + 256, nullptr, bufD);
    // 6. ffn2, K=512 over (bufC, bufD) -> bufB (y4)
    gemm_mfma<0, 16><<<gGrid, gBlk, 0, stream>>>(bufC, bufD, packH + 262144,
                                                 packL + 262144, ffn2_b, nullptr, bufB);
    // 7. proj_out + res2(bufA) -> bufC (h2)
    gemm_mfma<2, 8><<<gGrid, gBlk, 0, stream>>>(bufB, nullptr, packH + 393216,
                                                packL + 393216, po_b, bufA, bufC);
    // 8. post + res(x) -> d_out
    gemm_mfma<2, 8><<<gGrid, gBlk, 0, stream>>>(bufC, nullptr, packH + 458752,
                                                packL + 458752, post_b, x, (float*)d_out);
}